// Round 7
// baseline (1451.532 us; speedup 1.0000x reference)
//
#include <hip/hip_runtime.h>
#include <hip/hip_cooperative_groups.h>

namespace cg = cooperative_groups;

#define N 4096
#define NITER 100
// Mr = -(C/maxC)/0.05 in [-20,0]; q16 = round((C/maxC)*65535); Mr ~= -q16*DSTEP
#define DSTEP (20.0f / 65535.0f)
#define LOG2E 1.44269504088896340736f
#define DSTEP2 (DSTEP * LOG2E)
#define TOL 1e-4f
#define THETA 1.49f      // SOR factor: lambda~0.885 -> theta* = 2/(1+sqrt(1-lambda)) ~ 1.494
#define POLISH 2         // plain (theta=1) iterations after convergence fires
#define NB 256
#define NT 1024
#define ROWS 16                      // rows owned per block, u16-quantized in LDS
#define TILE_BYTES (ROWS * N * 2)    // 128 KiB

typedef unsigned short u16;
typedef unsigned long long u64;

// Cross-XCD-coherent accessors (per-XCD L2 NOT coherent; agent-scope atomics
// hit the device coherence point). ALL cross-block traffic uses these.
__device__ __forceinline__ float aload(const float* p) {
    return __hip_atomic_load(p, __ATOMIC_RELAXED, __HIP_MEMORY_SCOPE_AGENT);
}
__device__ __forceinline__ void astore(float* p, float x) {
    __hip_atomic_store(p, x, __ATOMIC_RELAXED, __HIP_MEMORY_SCOPE_AGENT);
}
__device__ __forceinline__ u64 aload64(const float* p) {
    return __hip_atomic_load((const u64*)p, __ATOMIC_RELAXED, __HIP_MEMORY_SCOPE_AGENT);
}
__device__ __forceinline__ void astore64(float* p, u64 x) {
    __hip_atomic_store((u64*)p, x, __ATOMIC_RELAXED, __HIP_MEMORY_SCOPE_AGENT);
}
__device__ __forceinline__ int aloadi(const int* p) {
    return __hip_atomic_load(p, __ATOMIC_RELAXED, __HIP_MEMORY_SCOPE_AGENT);
}

__device__ __forceinline__ float fexp2(float x) {
#if __has_builtin(__builtin_amdgcn_exp2f)
    return __builtin_amdgcn_exp2f(x);        // raw v_exp_f32
#else
    return __expf(x * 0.6931471805599453f);  // exp(x*ln2) == 2^x
#endif
}

// One persistent cooperative kernel. Over-relaxed log-domain Sinkhorn:
//   u <- (1-th)*u + th*(logp - LSE_row(Mr + v))
//   v <- v + th*(logq - log(sum_r exp(Mr + u_new + v)_r))   [= (1-th)v + th*v*]
// Same fixpoint as plain Sinkhorn; exit on max|dv| < TOL, then POLISH plain iters.
__global__ __launch_bounds__(NT) void ot_all(const float* __restrict__ p,
                                             const float* __restrict__ q,
                                             const float* __restrict__ C,
                                             int* maxC,
                                             int* dmax,
                                             float* v,
                                             float* part,
                                             float* __restrict__ out) {
    cg::grid_group grid = cg::this_grid();
    extern __shared__ u16 tile[];        // [ROWS][N] = 128 KiB
    const int t = threadIdx.x;
    const int b = blockIdx.x;
    const int lane = t & 63;
    const int wave = t >> 6;             // 0..15
    const int gid = b * NT + t;
    const int r0 = b * ROWS;             // owned rows (phase A / final)
    const int c0 = b * 16;               // owned cols (phase B)
    const int j0 = t * 4;                // per-thread col slice

    __shared__ float sred[4][16];
    __shared__ float wbc[4];
    __shared__ float s2[16][16];
    __shared__ float wm[16];
    __shared__ float lp[ROWS], lq[16], su[ROWS];
    __shared__ float dmf;

    // ---------------- phase 0: max over OWN rows (warms local L2 for phase 1) ----------------
    {
        const float4* Crow = (const float4*)(C + (size_t)r0 * N);
        float m = 0.f;
        for (int i = t; i < ROWS * N / 4; i += NT) {
            float4 c = Crow[i];
            m = fmaxf(m, fmaxf(fmaxf(c.x, c.y), fmaxf(c.z, c.w)));
        }
#pragma unroll
        for (int off = 32; off; off >>= 1) m = fmaxf(m, __shfl_down(m, off));
        if (lane == 0) wm[wave] = m;
        __syncthreads();
        if (t == 0) {
            m = wm[0];
#pragma unroll
            for (int i = 1; i < 16; ++i) m = fmaxf(m, wm[i]);
            atomicMax(maxC, __float_as_int(m));  // C >= 0: int order == float order
        }
    }
    grid.sync();
    const float qmul = 65535.0f / __int_as_float(aloadi(maxC));

    // ---------------- phase 1: quantize own rows into LDS + per-block scalars ----------------
    {
        const float4* Crow = (const float4*)(C + (size_t)r0 * N);
        uint2* T2 = (uint2*)tile;
        for (int i = t; i < ROWS * N / 4; i += NT) {
            float4 a = Crow[i];
            uint2 o;
            o.x = min(65535u, __float2uint_rn(a.x * qmul)) | (min(65535u, __float2uint_rn(a.y * qmul)) << 16);
            o.y = min(65535u, __float2uint_rn(a.z * qmul)) | (min(65535u, __float2uint_rn(a.w * qmul)) << 16);
            T2[i] = o;
        }
        if (t < ROWS) {
            lp[t] = __logf(p[r0 + t]);
            lq[t] = __logf(q[c0 + t]);
            su[t] = 0.f;                     // u0 = 0
        }
        if (gid < N) astore(&v[gid], 0.f);   // coherent v init
    }
    float vreg = 0.f;                        // own col's v (valid for t<16; only this block writes it)
    int plain_left = -1;                     // -1: accelerating; >0: plain polish countdown
    grid.sync();

    // ---------------- Sinkhorn iterations ----------------
    for (int it = 0; it < NITER; ++it) {
        const float th = (plain_left >= 0) ? 1.0f : THETA;

        // ---- phase A: S_r = sum_j exp(Mr+v_j); u_r relaxed; colpart_j += t_rj*exp(u_new_r) ----
        float vv2[4];
        {
            u64 a0 = aload64(v + j0), a1 = aload64(v + j0 + 2);
            vv2[0] = __uint_as_float((unsigned)a0) * LOG2E;
            vv2[1] = __uint_as_float((unsigned)(a0 >> 32)) * LOG2E;
            vv2[2] = __uint_as_float((unsigned)a1) * LOG2E;
            vv2[3] = __uint_as_float((unsigned)(a1 >> 32)) * LOG2E;
        }
        float ca[4] = {0.f, 0.f, 0.f, 0.f};

        for (int ch = 0; ch < 4; ++ch) {
            const int rl = ch * 4;
            float tq[4][4], sp[4];
#pragma unroll
            for (int r = 0; r < 4; ++r) {
                uint2 a = *(const uint2*)(tile + (size_t)(rl + r) * N + j0);
                float e0 = fexp2(fmaf((float)(a.x & 0xffffu), -DSTEP2, vv2[0]));
                float e1 = fexp2(fmaf((float)(a.x >> 16),     -DSTEP2, vv2[1]));
                float e2 = fexp2(fmaf((float)(a.y & 0xffffu), -DSTEP2, vv2[2]));
                float e3 = fexp2(fmaf((float)(a.y >> 16),     -DSTEP2, vv2[3]));
                tq[r][0] = e0; tq[r][1] = e1; tq[r][2] = e2; tq[r][3] = e3;
                sp[r] = (e0 + e1) + (e2 + e3);
            }
#pragma unroll
            for (int r = 0; r < 4; ++r) {
                float s = sp[r];
#pragma unroll
                for (int off = 32; off; off >>= 1) s += __shfl_down(s, off);
                if (lane == 0) sred[r][wave] = s;
            }
            __syncthreads();
            if (wave < 4) {  // wave w finalizes local row rl+w
                float s = (lane < 16) ? sred[wave][lane] : 0.f;
                s += __shfl_down(s, 8);
                s += __shfl_down(s, 4);
                s += __shfl_down(s, 2);
                s += __shfl_down(s, 1);
                if (lane == 0) {
                    const int r = rl + wave;
                    const float un = (1.f - th) * su[r] + th * (lp[r] - __logf(s));
                    su[r] = un;
                    wbc[wave] = fexp2(un * LOG2E);     // exp(u_new_r)
                }
            }
            __syncthreads();
#pragma unroll
            for (int r = 0; r < 4; ++r) {
                const float w = wbc[r];
#pragma unroll
                for (int k = 0; k < 4; ++k) ca[k] = fmaf(tq[r][k], w, ca[k]);
            }
        }
        {
            u64 w0 = (u64)__float_as_uint(ca[0]) | ((u64)__float_as_uint(ca[1]) << 32);
            u64 w1 = (u64)__float_as_uint(ca[2]) | ((u64)__float_as_uint(ca[3]) << 32);
            astore64(part + (size_t)b * N + j0, w0);
            astore64(part + (size_t)b * N + j0 + 2, w1);
        }
        grid.sync();

        // ---- phase B: v_j += th*(logq_j - log(sum_b part[b][j])) for 16 owned cols ----
        {
            const int cl = t & 15;       // col-local
            const int ch = t >> 4;       // 0..63 part-row group
            const int c = c0 + cl;
            float s = 0.f;
#pragma unroll
            for (int k = 0; k < 4; ++k) s += aload(&part[(size_t)(ch + 64 * k) * N + c]);
            s += __shfl_down(s, 16);
            s += __shfl_down(s, 32);
            if (lane < 16) s2[cl][wave] = s;
            __syncthreads();
            if (t < 16) {
                float tot = 0.f;
#pragma unroll
                for (int w = 0; w < 16; ++w) tot += s2[t][w];
                const float dv = th * (lq[t] - __logf(tot));
                const float vn = vreg + dv;
                astore(&v[c0 + t], vn);
                vreg = vn;
                float d = fabsf(dv);
                d = fmaxf(d, __shfl_down(d, 8));
                d = fmaxf(d, __shfl_down(d, 4));
                d = fmaxf(d, __shfl_down(d, 2));
                d = fmaxf(d, __shfl_down(d, 1));
                if (t == 0) atomicMax(dmax + it, __float_as_int(d));  // device-scope
            }
        }
        grid.sync();

        // ---- uniform decision: one coherent load of this iteration's global max|dv| ----
        if (t == 0) dmf = __int_as_float(aloadi(dmax + it));
        __syncthreads();
        const float dm = dmf;
        if (plain_left < 0) {
            if (dm < TOL) plain_left = POLISH;   // switch to plain polish iterations
        } else if (--plain_left == 0) {
            break;
        }
    }

    // ---------------- final: out rows from LDS tile + su + coherent v ----------------
    {
        float vvl[4];
        u64 a0 = aload64(v + j0), a1 = aload64(v + j0 + 2);
        vvl[0] = __uint_as_float((unsigned)a0) * LOG2E;
        vvl[1] = __uint_as_float((unsigned)(a0 >> 32)) * LOG2E;
        vvl[2] = __uint_as_float((unsigned)a1) * LOG2E;
        vvl[3] = __uint_as_float((unsigned)(a1 >> 32)) * LOG2E;
#pragma unroll 4
        for (int r = 0; r < ROWS; ++r) {
            const float uul = su[r] * LOG2E;
            uint2 a = *(const uint2*)(tile + (size_t)r * N + j0);
            float4 o;
            o.x = fexp2(fmaf((float)(a.x & 0xffffu), -DSTEP2, uul + vvl[0]));
            o.y = fexp2(fmaf((float)(a.x >> 16),     -DSTEP2, uul + vvl[1]));
            o.z = fexp2(fmaf((float)(a.y & 0xffffu), -DSTEP2, uul + vvl[2]));
            o.w = fexp2(fmaf((float)(a.y >> 16),     -DSTEP2, uul + vvl[3]));
            *(float4*)(out + (size_t)(r0 + r) * N + j0) = o;
        }
    }
}

extern "C" void kernel_launch(void* const* d_in, const int* in_sizes, int n_in,
                              void* d_out, int out_size, void* d_ws, size_t ws_size,
                              hipStream_t stream) {
    const float* p = (const float*)d_in[0];
    const float* q = (const float*)d_in[1];
    const float* C = (const float*)d_in[2];
    float* out = (float*)d_out;

    float* W = (float*)d_ws;
    int* maxC = (int*)W;                          // [0] must start 0
    int* dmax = (int*)(W + 1);                    // [1..NITER] must start 0
    float* v = W + 256;                           // N floats (init'd in-kernel)
    float* part = (float*)((char*)d_ws + 128 * 1024);   // NB x N f32 = 4 MB

    hipMemsetAsync(d_ws, 0, (1 + NITER) * sizeof(int), stream);  // maxC + dmax slots

    hipFuncSetAttribute((const void*)ot_all, hipFuncAttributeMaxDynamicSharedMemorySize, TILE_BYTES);

    void* args[] = {(void*)&p, (void*)&q, (void*)&C, (void*)&maxC,
                    (void*)&dmax, (void*)&v, (void*)&part, (void*)&out};
    hipLaunchCooperativeKernel((void*)ot_all, dim3(NB), dim3(NT), args, TILE_BYTES, stream);
}

// Round 8
// 969.796 us; speedup vs baseline: 1.4967x; 1.4967x over previous
//
#include <hip/hip_runtime.h>
#include <hip/hip_cooperative_groups.h>

namespace cg = cooperative_groups;

#define N 4096
#define NITER 100
// Mr = -(C/maxC)/0.05 in [-20,0]; q16 = round((C/maxC)*65535); Mr ~= -q16*DSTEP
#define DSTEP (20.0f / 65535.0f)
#define LOG2E 1.44269504088896340736f
#define DSTEP2 (DSTEP * LOG2E)
#define TOL 1e-4f
#define THETA 1.30f      // below theta* (~1.49): real eigenvalues, monotone decay, rho~0.78
#define POLISH 2         // plain (theta=1) iterations after convergence fires
#define NB 256
#define NT 1024
#define ROWS 16                      // rows owned per block, u16-quantized in LDS
#define TILE_BYTES (ROWS * N * 2)    // 128 KiB

typedef unsigned short u16;

// Cross-XCD-coherent accessors (per-XCD L2 NOT coherent; agent-scope atomics
// hit the device coherence point). ALL cross-block traffic uses these.
// 32-bit ONLY — round-7 showed 64-bit agent atomics + same-address atomicMax
// serialize and write through to HBM (4x per-iteration regression).
__device__ __forceinline__ float aload(const float* p) {
    return __hip_atomic_load(p, __ATOMIC_RELAXED, __HIP_MEMORY_SCOPE_AGENT);
}
__device__ __forceinline__ void astore(float* p, float x) {
    __hip_atomic_store(p, x, __ATOMIC_RELAXED, __HIP_MEMORY_SCOPE_AGENT);
}
__device__ __forceinline__ int aloadi(const int* p) {
    return __hip_atomic_load(p, __ATOMIC_RELAXED, __HIP_MEMORY_SCOPE_AGENT);
}

__device__ __forceinline__ float fexp2(float x) {
#if __has_builtin(__builtin_amdgcn_exp2f)
    return __builtin_amdgcn_exp2f(x);        // raw v_exp_f32
#else
    return __expf(x * 0.6931471805599453f);  // exp(x*ln2) == 2^x
#endif
}

// One persistent cooperative kernel. Over-relaxed log-domain Sinkhorn:
//   u <- u + th*((logp - LSE_row(Mr + v)) - u)
//   v <- v + th*(logq - log(sum_r exp(Mr + u_new + v)_r))
// Same fixpoint as plain Sinkhorn. Guard: if max|dv| grows, th -> 1 forever.
// Exit on max|dv| < TOL, then POLISH plain iterations.
__global__ __launch_bounds__(NT) void ot_all(const float* __restrict__ p,
                                             const float* __restrict__ q,
                                             const float* __restrict__ C,
                                             int* maxC,
                                             float* v,
                                             float* part,
                                             float* ddel,
                                             float* __restrict__ out) {
    cg::grid_group grid = cg::this_grid();
    extern __shared__ u16 tile[];        // [ROWS][N] = 128 KiB
    const int t = threadIdx.x;
    const int b = blockIdx.x;
    const int lane = t & 63;
    const int wave = t >> 6;             // 0..15
    const int gid = b * NT + t;
    const int r0 = b * ROWS;             // owned rows (phase A / final)
    const int c0 = b * 16;               // owned cols (phase B)
    const int j0 = t * 4;                // per-thread col slice

    __shared__ float sred[4][16];
    __shared__ float wbc[4];
    __shared__ float s2[16][16];
    __shared__ float dm[16];
    __shared__ float wm[16];
    __shared__ float lp[ROWS], lq[16], su[ROWS];

    // ---------------- phase 0: max over OWN rows (warms local L2 for phase 1) ----------------
    {
        const float4* Crow = (const float4*)(C + (size_t)r0 * N);
        float m = 0.f;
        for (int i = t; i < ROWS * N / 4; i += NT) {
            float4 c = Crow[i];
            m = fmaxf(m, fmaxf(fmaxf(c.x, c.y), fmaxf(c.z, c.w)));
        }
#pragma unroll
        for (int off = 32; off; off >>= 1) m = fmaxf(m, __shfl_down(m, off));
        if (lane == 0) wm[wave] = m;
        __syncthreads();
        if (t == 0) {
            m = wm[0];
#pragma unroll
            for (int i = 1; i < 16; ++i) m = fmaxf(m, wm[i]);
            atomicMax(maxC, __float_as_int(m));  // C >= 0: int order == float order
        }
    }
    grid.sync();
    const float qmul = 65535.0f / __int_as_float(aloadi(maxC));

    // ---------------- phase 1: quantize own rows into LDS + per-block scalars ----------------
    {
        const float4* Crow = (const float4*)(C + (size_t)r0 * N);
        uint2* T2 = (uint2*)tile;
        for (int i = t; i < ROWS * N / 4; i += NT) {
            float4 a = Crow[i];
            uint2 o;
            o.x = min(65535u, __float2uint_rn(a.x * qmul)) | (min(65535u, __float2uint_rn(a.y * qmul)) << 16);
            o.y = min(65535u, __float2uint_rn(a.z * qmul)) | (min(65535u, __float2uint_rn(a.w * qmul)) << 16);
            T2[i] = o;
        }
        if (t < ROWS) {
            lp[t] = __logf(p[r0 + t]);
            lq[t] = __logf(q[c0 + t]);
            su[t] = 0.f;                     // u0 = 0 (read by relaxed update at it=0)
        }
        if (gid < N) astore(&v[gid], 0.f);   // coherent v init
    }
    float vreg = 0.f;      // own col's v (valid for t<16; only this block writes it)
    float th = THETA;      // current relaxation factor (grid-uniform)
    float prev = 1e30f;    // previous iteration's max|dv| (grid-uniform)
    int polish = -1;       // -1: normal; >=0: plain polish countdown
    grid.sync();

    // ---------------- Sinkhorn iterations ----------------
    for (int it = 0; it < NITER; ++it) {
        // ---- phase A: S_r = sum_j exp(Mr+v_j); u_r relaxed; colpart_j += t_rj*exp(u_new_r) ----
        float vv2[4];
#pragma unroll
        for (int k = 0; k < 4; ++k) vv2[k] = aload(&v[j0 + k]) * LOG2E;
        float ca[4] = {0.f, 0.f, 0.f, 0.f};

        for (int ch = 0; ch < 4; ++ch) {
            const int rl = ch * 4;
            float tq[4][4], sp[4];
#pragma unroll
            for (int r = 0; r < 4; ++r) {
                uint2 a = *(const uint2*)(tile + (size_t)(rl + r) * N + j0);
                float e0 = fexp2(fmaf((float)(a.x & 0xffffu), -DSTEP2, vv2[0]));
                float e1 = fexp2(fmaf((float)(a.x >> 16),     -DSTEP2, vv2[1]));
                float e2 = fexp2(fmaf((float)(a.y & 0xffffu), -DSTEP2, vv2[2]));
                float e3 = fexp2(fmaf((float)(a.y >> 16),     -DSTEP2, vv2[3]));
                tq[r][0] = e0; tq[r][1] = e1; tq[r][2] = e2; tq[r][3] = e3;
                sp[r] = (e0 + e1) + (e2 + e3);
            }
#pragma unroll
            for (int r = 0; r < 4; ++r) {
                float s = sp[r];
#pragma unroll
                for (int off = 32; off; off >>= 1) s += __shfl_down(s, off);
                if (lane == 0) sred[r][wave] = s;
            }
            __syncthreads();
            if (wave < 4) {  // wave w finalizes local row rl+w
                float s = (lane < 16) ? sred[wave][lane] : 0.f;
                s += __shfl_down(s, 8);
                s += __shfl_down(s, 4);
                s += __shfl_down(s, 2);
                s += __shfl_down(s, 1);
                if (lane == 0) {
                    const int r = rl + wave;
                    const float un = fmaf(th, (lp[r] - __logf(s)) - su[r], su[r]);
                    su[r] = un;
                    wbc[wave] = fexp2(un * LOG2E);     // exp(u_new_r)
                }
            }
            __syncthreads();
#pragma unroll
            for (int r = 0; r < 4; ++r) {
                const float w = wbc[r];
#pragma unroll
                for (int k = 0; k < 4; ++k) ca[k] = fmaf(tq[r][k], w, ca[k]);
            }
        }
#pragma unroll
        for (int k = 0; k < 4; ++k) astore(&part[(size_t)b * N + j0 + k], ca[k]);
        grid.sync();

        // ---- phase B: v_j += th*(logq_j - log(sum_b part[b][j])) for 16 owned cols ----
        {
            const int cl = t & 15;       // col-local
            const int ch = t >> 4;       // 0..63 part-row group
            const int c = c0 + cl;
            float s = 0.f;
#pragma unroll
            for (int k = 0; k < 4; ++k) s += aload(&part[(size_t)(ch + 64 * k) * N + c]);
            s += __shfl_down(s, 16);
            s += __shfl_down(s, 32);
            if (lane < 16) s2[cl][wave] = s;
            __syncthreads();
            if (t < 16) {
                float tot = 0.f;
#pragma unroll
                for (int w = 0; w < 16; ++w) tot += s2[t][w];
                const float dv = th * (lq[t] - __logf(tot));
                const float vn = vreg + dv;
                astore(&v[c0 + t], vn);
                vreg = vn;
                float d = fabsf(dv);
                d = fmaxf(d, __shfl_down(d, 8));
                d = fmaxf(d, __shfl_down(d, 4));
                d = fmaxf(d, __shfl_down(d, 2));
                d = fmaxf(d, __shfl_down(d, 1));
                if (t == 0) astore(&ddel[b], d);       // per-block slot (no contention)
            }
        }
        grid.sync();

        // ---- uniform convergence check + relaxation state machine ----
        {
            float d = aload(&ddel[t & 255]);
#pragma unroll
            for (int off = 32; off; off >>= 1) d = fmaxf(d, __shfl_down(d, off));
            if (lane == 0) dm[wave] = d;
            __syncthreads();
            float m = dm[0];
#pragma unroll
            for (int w = 1; w < 16; ++w) m = fmaxf(m, dm[w]);
            __syncthreads();
            // grid-uniform decisions (m identical in every block/thread)
            if (polish >= 0) {
                if (--polish < 0) break;                 // polish done
            } else if (m < TOL) {
                polish = POLISH - 1;                     // POLISH plain iters, then exit
                th = 1.0f;
            } else if (it >= 5 && m > prev * 1.05f) {
                th = 1.0f;                               // oscillation guard: plain forever
            }
            prev = m;
        }
    }

    // ---------------- final: out rows from LDS tile + su + coherent v ----------------
    {
        float vvl[4];
#pragma unroll
        for (int k = 0; k < 4; ++k) vvl[k] = aload(&v[j0 + k]) * LOG2E;
#pragma unroll 4
        for (int r = 0; r < ROWS; ++r) {
            const float uul = su[r] * LOG2E;
            uint2 a = *(const uint2*)(tile + (size_t)r * N + j0);
            float4 o;
            o.x = fexp2(fmaf((float)(a.x & 0xffffu), -DSTEP2, uul + vvl[0]));
            o.y = fexp2(fmaf((float)(a.x >> 16),     -DSTEP2, uul + vvl[1]));
            o.z = fexp2(fmaf((float)(a.y & 0xffffu), -DSTEP2, uul + vvl[2]));
            o.w = fexp2(fmaf((float)(a.y >> 16),     -DSTEP2, uul + vvl[3]));
            *(float4*)(out + (size_t)(r0 + r) * N + j0) = o;
        }
    }
}

extern "C" void kernel_launch(void* const* d_in, const int* in_sizes, int n_in,
                              void* d_out, int out_size, void* d_ws, size_t ws_size,
                              hipStream_t stream) {
    const float* p = (const float*)d_in[0];
    const float* q = (const float*)d_in[1];
    const float* C = (const float*)d_in[2];
    float* out = (float*)d_out;

    float* W = (float*)d_ws;
    int* maxC = (int*)W;                          // must start 0
    float* v = W + 16;                            // N floats (init'd in-kernel)
    float* ddel = v + N;                          // NB floats (written before read)
    float* part = (float*)((char*)d_ws + 128 * 1024);   // NB x N f32 = 4 MB

    hipMemsetAsync(d_ws, 0, 64, stream);  // zero maxC

    hipFuncSetAttribute((const void*)ot_all, hipFuncAttributeMaxDynamicSharedMemorySize, TILE_BYTES);

    void* args[] = {(void*)&p, (void*)&q, (void*)&C, (void*)&maxC,
                    (void*)&v, (void*)&part, (void*)&ddel, (void*)&out};
    hipLaunchCooperativeKernel((void*)ot_all, dim3(NB), dim3(NT), args, TILE_BYTES, stream);
}

// Round 9
// 302.401 us; speedup vs baseline: 4.8000x; 3.2070x over previous
//
#include <hip/hip_runtime.h>
#include <hip/hip_cooperative_groups.h>

namespace cg = cooperative_groups;

#define N 4096
#define NITER 100
// Mr = -(C/maxC)/0.05 in [-20,0]; q16 = round((C/maxC)*65535); Mr ~= -q16*DSTEP
#define DSTEP (20.0f / 65535.0f)
#define LOG2E 1.44269504088896340736f
#define DSTEP2 (DSTEP * LOG2E)
#define TOL 1e-4f        // R5-validated: TOL=1e-4 exit + direct final == 100-iter reference (absmax 2.98e-8)
#define NB 256
#define NT 1024
#define ROWS 16                      // rows owned per block, u16-quantized in LDS
#define TILE_BYTES (ROWS * N * 2)    // 128 KiB

typedef unsigned short u16;

// Cross-XCD-coherent accessors (per-XCD L2 NOT coherent; agent-scope atomics
// hit the device coherence point). ALL cross-block traffic uses these.
// 32-bit ONLY (round-7: 64-bit agent atomics regressed 4x). NO SOR (rounds
// 7/8: over-relaxation increases iteration count on this fast-contracting map).
__device__ __forceinline__ float aload(const float* p) {
    return __hip_atomic_load(p, __ATOMIC_RELAXED, __HIP_MEMORY_SCOPE_AGENT);
}
__device__ __forceinline__ void astore(float* p, float x) {
    __hip_atomic_store(p, x, __ATOMIC_RELAXED, __HIP_MEMORY_SCOPE_AGENT);
}
__device__ __forceinline__ int aloadi(const int* p) {
    return __hip_atomic_load(p, __ATOMIC_RELAXED, __HIP_MEMORY_SCOPE_AGENT);
}

__device__ __forceinline__ float fexp2(float x) {
#if __has_builtin(__builtin_amdgcn_exp2f)
    return __builtin_amdgcn_exp2f(x);        // raw v_exp_f32
#else
    return __expf(x * 0.6931471805599453f);  // exp(x*ln2) == 2^x
#endif
}

// One persistent cooperative kernel (R6 structure, proven stable):
//   phase 0: max over own rows                         -> grid.sync
//   phase 1: quantize own 16 rows into LDS; init       -> grid.sync
//   loop: A (u-update in LDS + per-block col partials) -> grid.sync
//         B (reduce partials -> v-update, delta)       -> grid.sync
//         uniform convergence check (m < TOL) -> break
//   final: out rows = exp(-q*DSTEP + u + v) from LDS tile
__global__ __launch_bounds__(NT) void ot_all(const float* __restrict__ p,
                                             const float* __restrict__ q,
                                             const float* __restrict__ C,
                                             int* maxC,
                                             float* v,
                                             float* part,
                                             float* ddel,
                                             float* __restrict__ out) {
    cg::grid_group grid = cg::this_grid();
    extern __shared__ u16 tile[];        // [ROWS][N] = 128 KiB
    const int t = threadIdx.x;
    const int b = blockIdx.x;
    const int lane = t & 63;
    const int wave = t >> 6;             // 0..15
    const int gid = b * NT + t;
    const int r0 = b * ROWS;             // owned rows (phase A / final)
    const int c0 = b * 16;               // owned cols (phase B)
    const int j0 = t * 4;                // per-thread col slice

    __shared__ float sred[4][16];
    __shared__ float wbc[4];
    __shared__ float s2[16][16];
    __shared__ float dm[16];
    __shared__ float wm[16];
    __shared__ float lp[ROWS], pp[ROWS], lq[16], su[ROWS];

    // ---------------- phase 0: max over OWN rows (warms local L2 for phase 1) ----------------
    {
        const float4* Crow = (const float4*)(C + (size_t)r0 * N);
        float m = 0.f;
        for (int i = t; i < ROWS * N / 4; i += NT) {
            float4 c = Crow[i];
            m = fmaxf(m, fmaxf(fmaxf(c.x, c.y), fmaxf(c.z, c.w)));
        }
#pragma unroll
        for (int off = 32; off; off >>= 1) m = fmaxf(m, __shfl_down(m, off));
        if (lane == 0) wm[wave] = m;
        __syncthreads();
        if (t == 0) {
            m = wm[0];
#pragma unroll
            for (int i = 1; i < 16; ++i) m = fmaxf(m, wm[i]);
            atomicMax(maxC, __float_as_int(m));  // C >= 0: int order == float order
        }
    }
    grid.sync();
    const float qmul = 65535.0f / __int_as_float(aloadi(maxC));

    // ---------------- phase 1: quantize own rows into LDS + per-block scalars ----------------
    {
        const float4* Crow = (const float4*)(C + (size_t)r0 * N);
        uint2* T2 = (uint2*)tile;
        for (int i = t; i < ROWS * N / 4; i += NT) {
            float4 a = Crow[i];
            uint2 o;
            o.x = min(65535u, __float2uint_rn(a.x * qmul)) | (min(65535u, __float2uint_rn(a.y * qmul)) << 16);
            o.y = min(65535u, __float2uint_rn(a.z * qmul)) | (min(65535u, __float2uint_rn(a.w * qmul)) << 16);
            T2[i] = o;
        }
        if (t < ROWS) {
            float pv = p[r0 + t];
            pp[t] = pv;
            lp[t] = __logf(pv);
            lq[t] = __logf(q[c0 + t]);
            su[t] = 0.f;
        }
        if (gid < N) astore(&v[gid], 0.f);   // coherent v init
    }
    float vreg = 0.f;      // own col's v (valid for t<16; only this block writes it)
    grid.sync();

    // ---------------- Sinkhorn iterations (plain, Gauss-Seidel) ----------------
    for (int it = 0; it < NITER; ++it) {
        // ---- phase A: S_r = sum_j exp(Mr+v_j); u_r = logp_r - log S_r;
        //      colpart_j += t_rj * (p_r/S_r) ----
        float vv2[4];
#pragma unroll
        for (int k = 0; k < 4; ++k) vv2[k] = aload(&v[j0 + k]) * LOG2E;
        float ca[4] = {0.f, 0.f, 0.f, 0.f};

        for (int ch = 0; ch < 4; ++ch) {
            const int rl = ch * 4;
            float tq[4][4], sp[4];
#pragma unroll
            for (int r = 0; r < 4; ++r) {
                uint2 a = *(const uint2*)(tile + (size_t)(rl + r) * N + j0);
                float e0 = fexp2(fmaf((float)(a.x & 0xffffu), -DSTEP2, vv2[0]));
                float e1 = fexp2(fmaf((float)(a.x >> 16),     -DSTEP2, vv2[1]));
                float e2 = fexp2(fmaf((float)(a.y & 0xffffu), -DSTEP2, vv2[2]));
                float e3 = fexp2(fmaf((float)(a.y >> 16),     -DSTEP2, vv2[3]));
                tq[r][0] = e0; tq[r][1] = e1; tq[r][2] = e2; tq[r][3] = e3;
                sp[r] = (e0 + e1) + (e2 + e3);
            }
#pragma unroll
            for (int r = 0; r < 4; ++r) {
                float s = sp[r];
#pragma unroll
                for (int off = 32; off; off >>= 1) s += __shfl_down(s, off);
                if (lane == 0) sred[r][wave] = s;
            }
            __syncthreads();
            if (wave < 4) {  // wave w finalizes local row rl+w
                float s = (lane < 16) ? sred[wave][lane] : 0.f;
                s += __shfl_down(s, 8);
                s += __shfl_down(s, 4);
                s += __shfl_down(s, 2);
                s += __shfl_down(s, 1);
                if (lane == 0) {
                    wbc[wave] = pp[rl + wave] / s;             // exp(u_new_r)
                    su[rl + wave] = lp[rl + wave] - __logf(s); // u_new_r (block-local)
                }
            }
            __syncthreads();
#pragma unroll
            for (int r = 0; r < 4; ++r) {
                const float w = wbc[r];
#pragma unroll
                for (int k = 0; k < 4; ++k) ca[k] = fmaf(tq[r][k], w, ca[k]);
            }
        }
#pragma unroll
        for (int k = 0; k < 4; ++k) astore(&part[(size_t)b * N + j0 + k], ca[k]);
        grid.sync();

        // ---- phase B: v_j = logq_j + v_old_j - log( sum_b part[b][j] ) for 16 owned cols ----
        {
            const int cl = t & 15;       // col-local
            const int ch = t >> 4;       // 0..63 part-row group
            const int c = c0 + cl;
            float s = 0.f;
#pragma unroll
            for (int k = 0; k < 4; ++k) s += aload(&part[(size_t)(ch + 64 * k) * N + c]);
            s += __shfl_down(s, 16);
            s += __shfl_down(s, 32);
            if (lane < 16) s2[cl][wave] = s;
            __syncthreads();
            if (t < 16) {
                float tot = 0.f;
#pragma unroll
                for (int w = 0; w < 16; ++w) tot += s2[t][w];
                const float vn = lq[t] + vreg - __logf(tot);
                astore(&v[c0 + t], vn);
                float d = fabsf(vn - vreg);
                vreg = vn;
                d = fmaxf(d, __shfl_down(d, 8));
                d = fmaxf(d, __shfl_down(d, 4));
                d = fmaxf(d, __shfl_down(d, 2));
                d = fmaxf(d, __shfl_down(d, 1));
                if (t == 0) astore(&ddel[b], d);       // per-block slot (no contention)
            }
        }
        grid.sync();

        // ---- uniform convergence check (coherent ddel -> identical m in every block) ----
        {
            float d = aload(&ddel[t & 255]);
#pragma unroll
            for (int off = 32; off; off >>= 1) d = fmaxf(d, __shfl_down(d, off));
            if (lane == 0) dm[wave] = d;
            __syncthreads();
            float m = dm[0];
#pragma unroll
            for (int w = 1; w < 16; ++w) m = fmaxf(m, dm[w]);
            __syncthreads();
            if (m < TOL) break;
        }
    }

    // ---------------- final: out rows from LDS tile + su + coherent v ----------------
    {
        float vvl[4];
#pragma unroll
        for (int k = 0; k < 4; ++k) vvl[k] = aload(&v[j0 + k]) * LOG2E;
#pragma unroll 4
        for (int r = 0; r < ROWS; ++r) {
            const float uul = su[r] * LOG2E;
            uint2 a = *(const uint2*)(tile + (size_t)r * N + j0);
            float4 o;
            o.x = fexp2(fmaf((float)(a.x & 0xffffu), -DSTEP2, uul + vvl[0]));
            o.y = fexp2(fmaf((float)(a.x >> 16),     -DSTEP2, uul + vvl[1]));
            o.z = fexp2(fmaf((float)(a.y & 0xffffu), -DSTEP2, uul + vvl[2]));
            o.w = fexp2(fmaf((float)(a.y >> 16),     -DSTEP2, uul + vvl[3]));
            *(float4*)(out + (size_t)(r0 + r) * N + j0) = o;
        }
    }
}

extern "C" void kernel_launch(void* const* d_in, const int* in_sizes, int n_in,
                              void* d_out, int out_size, void* d_ws, size_t ws_size,
                              hipStream_t stream) {
    const float* p = (const float*)d_in[0];
    const float* q = (const float*)d_in[1];
    const float* C = (const float*)d_in[2];
    float* out = (float*)d_out;

    float* W = (float*)d_ws;
    int* maxC = (int*)W;                          // must start 0
    float* v = W + 16;                            // N floats (init'd in-kernel)
    float* ddel = v + N;                          // NB floats (written before read)
    float* part = (float*)((char*)d_ws + 128 * 1024);   // NB x N f32 = 4 MB

    hipMemsetAsync(d_ws, 0, 64, stream);  // zero maxC

    hipFuncSetAttribute((const void*)ot_all, hipFuncAttributeMaxDynamicSharedMemorySize, TILE_BYTES);

    void* args[] = {(void*)&p, (void*)&q, (void*)&C, (void*)&maxC,
                    (void*)&v, (void*)&part, (void*)&ddel, (void*)&out};
    hipLaunchCooperativeKernel((void*)ot_all, dim3(NB), dim3(NT), args, TILE_BYTES, stream);
}

// Round 10
// 205.943 us; speedup vs baseline: 7.0482x; 1.4684x over previous
//
#include <hip/hip_runtime.h>

#define N 4096
#define NITER 100
// Mr = -(C/maxC)/0.05 in [-20,0]; q16 = round((C/maxC)*65535); Mr ~= -q16*DSTEP
#define DSTEP (20.0f / 65535.0f)
#define LOG2E 1.44269504088896340736f
#define DSTEP2 (DSTEP * LOG2E)
#define TOL 3e-4f        // lambda~0.45: residual after exit ~2.5e-4 on v -> plan err ~2.5e-9 << 7e-8 slack
#define NB 256
#define NT 1024
#define ROWS 16                      // rows owned per block, u16-quantized in LDS
#define TILE_BYTES (ROWS * N * 2)    // 128 KiB

typedef unsigned short u16;

// Cross-XCD-coherent accessors (per-XCD L2 NOT coherent; agent-scope atomics
// hit the device coherence point). ALL cross-block traffic uses these.
// 32-bit ONLY (R7: 64-bit agent atomics regressed). NO SOR (R7/R8: slower).
__device__ __forceinline__ float aload(const float* p) {
    return __hip_atomic_load(p, __ATOMIC_RELAXED, __HIP_MEMORY_SCOPE_AGENT);
}
__device__ __forceinline__ void astore(float* p, float x) {
    __hip_atomic_store(p, x, __ATOMIC_RELAXED, __HIP_MEMORY_SCOPE_AGENT);
}
__device__ __forceinline__ int aloadi(const int* p) {
    return __hip_atomic_load(p, __ATOMIC_RELAXED, __HIP_MEMORY_SCOPE_AGENT);
}

__device__ __forceinline__ float fexp2(float x) {
#if __has_builtin(__builtin_amdgcn_exp2f)
    return __builtin_amdgcn_exp2f(x);        // raw v_exp_f32
#else
    return __expf(x * 0.6931471805599453f);  // exp(x*ln2) == 2^x
#endif
}

// Hand-rolled one-shot slot barrier. Each barrier event uses a fresh counter
// (memset-zeroed each launch). RELEASE on arrival orders our prior agent-scope
// stores; ACQUIRE on the spin load orders subsequent loads. Only thread 0
// spins; block-level ordering via __syncthreads. All control flow reaching a
// given slot is grid-uniform -> every block arrives at every used slot.
__device__ __forceinline__ void gbar(int* bar, int slot) {
    __syncthreads();
    if (threadIdx.x == 0) {
        __hip_atomic_fetch_add(&bar[slot], 1, __ATOMIC_RELEASE, __HIP_MEMORY_SCOPE_AGENT);
        while (__hip_atomic_load(&bar[slot], __ATOMIC_ACQUIRE, __HIP_MEMORY_SCOPE_AGENT) < NB)
            __builtin_amdgcn_s_sleep(1);
    }
    __syncthreads();
}

// One persistent co-resident kernel (R9 structure; only the barrier changed):
//   phase 0: max over own rows                         -> gbar
//   phase 1: quantize own 16 rows into LDS; init       -> gbar
//   loop: A (u-update in LDS + per-block col partials) -> gbar
//         B (reduce partials -> v-update, delta)       -> gbar
//         uniform convergence check (m < TOL) -> break
//   final: out rows = exp(-q*DSTEP + u + v) from LDS tile
__global__ __launch_bounds__(NT) void ot_all(const float* __restrict__ p,
                                             const float* __restrict__ q,
                                             const float* __restrict__ C,
                                             int* maxC,
                                             int* bar,
                                             float* v,
                                             float* part,
                                             float* ddel,
                                             float* __restrict__ out) {
    extern __shared__ u16 tile[];        // [ROWS][N] = 128 KiB
    const int t = threadIdx.x;
    const int b = blockIdx.x;
    const int lane = t & 63;
    const int wave = t >> 6;             // 0..15
    const int gid = b * NT + t;
    const int r0 = b * ROWS;             // owned rows (phase A / final)
    const int c0 = b * 16;               // owned cols (phase B)
    const int j0 = t * 4;                // per-thread col slice
    int slot = 0;                        // barrier event index (grid-uniform)

    __shared__ float sred[4][16];
    __shared__ float wbc[4];
    __shared__ float s2[16][16];
    __shared__ float dm[16];
    __shared__ float wm[16];
    __shared__ float lp[ROWS], pp[ROWS], lq[16], su[ROWS];

    // ---------------- phase 0: max over OWN rows (warms local L2 for phase 1) ----------------
    {
        const float4* Crow = (const float4*)(C + (size_t)r0 * N);
        float m = 0.f;
        for (int i = t; i < ROWS * N / 4; i += NT) {
            float4 c = Crow[i];
            m = fmaxf(m, fmaxf(fmaxf(c.x, c.y), fmaxf(c.z, c.w)));
        }
#pragma unroll
        for (int off = 32; off; off >>= 1) m = fmaxf(m, __shfl_down(m, off));
        if (lane == 0) wm[wave] = m;
        __syncthreads();
        if (t == 0) {
            m = wm[0];
#pragma unroll
            for (int i = 1; i < 16; ++i) m = fmaxf(m, wm[i]);
            atomicMax(maxC, __float_as_int(m));  // C >= 0: int order == float order
        }
    }
    gbar(bar, slot++);
    const float qmul = 65535.0f / __int_as_float(aloadi(maxC));

    // ---------------- phase 1: quantize own rows into LDS + per-block scalars ----------------
    {
        const float4* Crow = (const float4*)(C + (size_t)r0 * N);
        uint2* T2 = (uint2*)tile;
        for (int i = t; i < ROWS * N / 4; i += NT) {
            float4 a = Crow[i];
            uint2 o;
            o.x = min(65535u, __float2uint_rn(a.x * qmul)) | (min(65535u, __float2uint_rn(a.y * qmul)) << 16);
            o.y = min(65535u, __float2uint_rn(a.z * qmul)) | (min(65535u, __float2uint_rn(a.w * qmul)) << 16);
            T2[i] = o;
        }
        if (t < ROWS) {
            float pv = p[r0 + t];
            pp[t] = pv;
            lp[t] = __logf(pv);
            lq[t] = __logf(q[c0 + t]);
            su[t] = 0.f;
        }
        if (gid < N) astore(&v[gid], 0.f);   // coherent v init
    }
    float vreg = 0.f;      // own col's v (valid for t<16; only this block writes it)
    gbar(bar, slot++);

    // ---------------- Sinkhorn iterations (plain, Gauss-Seidel) ----------------
    for (int it = 0; it < NITER; ++it) {
        // ---- phase A: S_r = sum_j exp(Mr+v_j); u_r = logp_r - log S_r;
        //      colpart_j += t_rj * (p_r/S_r) ----
        float vv2[4];
#pragma unroll
        for (int k = 0; k < 4; ++k) vv2[k] = aload(&v[j0 + k]) * LOG2E;
        float ca[4] = {0.f, 0.f, 0.f, 0.f};

        for (int ch = 0; ch < 4; ++ch) {
            const int rl = ch * 4;
            float tq[4][4], sp[4];
#pragma unroll
            for (int r = 0; r < 4; ++r) {
                uint2 a = *(const uint2*)(tile + (size_t)(rl + r) * N + j0);
                float e0 = fexp2(fmaf((float)(a.x & 0xffffu), -DSTEP2, vv2[0]));
                float e1 = fexp2(fmaf((float)(a.x >> 16),     -DSTEP2, vv2[1]));
                float e2 = fexp2(fmaf((float)(a.y & 0xffffu), -DSTEP2, vv2[2]));
                float e3 = fexp2(fmaf((float)(a.y >> 16),     -DSTEP2, vv2[3]));
                tq[r][0] = e0; tq[r][1] = e1; tq[r][2] = e2; tq[r][3] = e3;
                sp[r] = (e0 + e1) + (e2 + e3);
            }
#pragma unroll
            for (int r = 0; r < 4; ++r) {
                float s = sp[r];
#pragma unroll
                for (int off = 32; off; off >>= 1) s += __shfl_down(s, off);
                if (lane == 0) sred[r][wave] = s;
            }
            __syncthreads();
            if (wave < 4) {  // wave w finalizes local row rl+w
                float s = (lane < 16) ? sred[wave][lane] : 0.f;
                s += __shfl_down(s, 8);
                s += __shfl_down(s, 4);
                s += __shfl_down(s, 2);
                s += __shfl_down(s, 1);
                if (lane == 0) {
                    wbc[wave] = pp[rl + wave] / s;             // exp(u_new_r)
                    su[rl + wave] = lp[rl + wave] - __logf(s); // u_new_r (block-local)
                }
            }
            __syncthreads();
#pragma unroll
            for (int r = 0; r < 4; ++r) {
                const float w = wbc[r];
#pragma unroll
                for (int k = 0; k < 4; ++k) ca[k] = fmaf(tq[r][k], w, ca[k]);
            }
        }
#pragma unroll
        for (int k = 0; k < 4; ++k) astore(&part[(size_t)b * N + j0 + k], ca[k]);
        gbar(bar, slot++);

        // ---- phase B: v_j = logq_j + v_old_j - log( sum_b part[b][j] ) for 16 owned cols ----
        {
            const int cl = t & 15;       // col-local
            const int ch = t >> 4;       // 0..63 part-row group
            const int c = c0 + cl;
            float s = 0.f;
#pragma unroll
            for (int k = 0; k < 4; ++k) s += aload(&part[(size_t)(ch + 64 * k) * N + c]);
            s += __shfl_down(s, 16);
            s += __shfl_down(s, 32);
            if (lane < 16) s2[cl][wave] = s;
            __syncthreads();
            if (t < 16) {
                float tot = 0.f;
#pragma unroll
                for (int w = 0; w < 16; ++w) tot += s2[t][w];
                const float vn = lq[t] + vreg - __logf(tot);
                astore(&v[c0 + t], vn);
                float d = fabsf(vn - vreg);
                vreg = vn;
                d = fmaxf(d, __shfl_down(d, 8));
                d = fmaxf(d, __shfl_down(d, 4));
                d = fmaxf(d, __shfl_down(d, 2));
                d = fmaxf(d, __shfl_down(d, 1));
                if (t == 0) astore(&ddel[b], d);       // per-block slot (no contention)
            }
        }
        gbar(bar, slot++);

        // ---- uniform convergence check (coherent ddel -> identical m in every block) ----
        {
            float d = aload(&ddel[t & 255]);
#pragma unroll
            for (int off = 32; off; off >>= 1) d = fmaxf(d, __shfl_down(d, off));
            if (lane == 0) dm[wave] = d;
            __syncthreads();
            float m = dm[0];
#pragma unroll
            for (int w = 1; w < 16; ++w) m = fmaxf(m, dm[w]);
            __syncthreads();
            if (m < TOL) break;
        }
    }

    // ---------------- final: out rows from LDS tile + su + coherent v ----------------
    {
        float vvl[4];
#pragma unroll
        for (int k = 0; k < 4; ++k) vvl[k] = aload(&v[j0 + k]) * LOG2E;
#pragma unroll 4
        for (int r = 0; r < ROWS; ++r) {
            const float uul = su[r] * LOG2E;
            uint2 a = *(const uint2*)(tile + (size_t)r * N + j0);
            float4 o;
            o.x = fexp2(fmaf((float)(a.x & 0xffffu), -DSTEP2, uul + vvl[0]));
            o.y = fexp2(fmaf((float)(a.x >> 16),     -DSTEP2, uul + vvl[1]));
            o.z = fexp2(fmaf((float)(a.y & 0xffffu), -DSTEP2, uul + vvl[2]));
            o.w = fexp2(fmaf((float)(a.y >> 16),     -DSTEP2, uul + vvl[3]));
            *(float4*)(out + (size_t)(r0 + r) * N + j0) = o;
        }
    }
}

extern "C" void kernel_launch(void* const* d_in, const int* in_sizes, int n_in,
                              void* d_out, int out_size, void* d_ws, size_t ws_size,
                              hipStream_t stream) {
    const float* p = (const float*)d_in[0];
    const float* q = (const float*)d_in[1];
    const float* C = (const float*)d_in[2];
    float* out = (float*)d_out;

    float* W = (float*)d_ws;
    int* maxC = (int*)W;                          // [0], must start 0
    int* bar = (int*)(W + 16);                    // 256 one-shot barrier slots, must start 0
    float* v = W + 512;                           // N floats (init'd in-kernel)
    float* ddel = v + N;                          // NB floats (written before read)
    float* part = (float*)((char*)d_ws + 128 * 1024);   // NB x N f32 = 4 MB

    hipMemsetAsync(d_ws, 0, 2048, stream);  // zero maxC + barrier slots

    hipFuncSetAttribute((const void*)ot_all, hipFuncAttributeMaxDynamicSharedMemorySize, TILE_BYTES);

    void* args[] = {(void*)&p, (void*)&q, (void*)&C, (void*)&maxC, (void*)&bar,
                    (void*)&v, (void*)&part, (void*)&ddel, (void*)&out};
    hipLaunchCooperativeKernel((void*)ot_all, dim3(NB), dim3(NT), args, TILE_BYTES, stream);
}